// Round 3
// baseline (297.217 us; speedup 1.0000x reference)
//
#include <hip/hip_runtime.h>

// LengthRegulator: B=32, T_src=1024, H=512 fixed by the problem.
// d_out layout: [expanded (B*max_len*H) f32][mel_masks (B*max_len) f32(0/1)]
// max_len recovered from out_size = B*max_len*(H+1).
//
// R6: single fused kernel, all 256 CUs.
//   - Each block (64 blocks/batch) redundantly scans its batch's 1024
//     durations (4 KB) in LDS: int4 load -> wave shuffle-scan -> combine 4
//     wave partials. Cheap (~2 barriers) and removes the lr_prep kernel,
//     its 32-CU serialization, the cum[] global round-trip, and the launch gap.
//   - x-row loads issued BEFORE the scan (addresses independent of cum) so
//     HBM latency hides under the scan.
//   - Each wave replicates ROWS_PER_WAVE=4 consecutive source rows ->
//     contiguous store ranges. Plain stores (A/B vs R5's nontemporal: x has
//     zero reuse, nothing in L2 worth protecting; the 6.5 TB/s fill uses
//     plain stores).
//   - Pad-tail zeroing + mask writes distributed across the batch's 256 waves.
//   Traffic floor: 64 MB x + ~8 MB dur re-reads (L2) + 248 MB writes ~ 55 us.

#define B_SZ   32
#define T_SRC  1024
#define H_DIM  512
#define BLK_PER_B     64                    // blocks per batch row
#define ROWS_PER_BLK  (T_SRC / BLK_PER_B)   // 16
#define ROWS_PER_WAVE (ROWS_PER_BLK / 4)    // 4

typedef float f4 __attribute__((ext_vector_type(4)));
typedef int   i4 __attribute__((ext_vector_type(4)));

__global__ void __launch_bounds__(256) lr_fused(const float* __restrict__ x,
                                                const int* __restrict__ dur,
                                                float* __restrict__ out,
                                                float* __restrict__ mask,
                                                int max_len) {
    __shared__ int cumsh[T_SRC];   // inclusive cumsum of this batch's durations
    __shared__ int wsum[4];

    const int b    = blockIdx.y;
    const int bx   = blockIdx.x;
    const int tid  = threadIdx.x;
    const int lane = tid & 63;
    const int wid  = tid >> 6;

    // ---- issue x-row loads first: addresses are pure (b,s), overlap the scan
    const int r0 = bx * ROWS_PER_BLK + wid * ROWS_PER_WAVE;
    const float* xb = x + (size_t)b * T_SRC * H_DIM;
    f4 v0[ROWS_PER_WAVE], v1[ROWS_PER_WAVE];
#pragma unroll
    for (int i = 0; i < ROWS_PER_WAVE; ++i) {
        const f4* src = (const f4*)(xb + (size_t)(r0 + i) * H_DIM);
        v0[i] = src[lane];
        v1[i] = src[lane + 64];
    }

    // ---- block-wide inclusive scan of 1024 durations (4 ints/thread) ----
    i4 d = ((const i4*)(dur + b * T_SRC))[tid];
    const int s0 = d.x, s1 = s0 + d.y, s2 = s1 + d.z, s3 = s2 + d.w;
    int v = s3;                                  // wave shuffle-scan of group sums
#pragma unroll
    for (int off = 1; off < 64; off <<= 1) {
        int u = __shfl_up(v, off);
        if (lane >= off) v += u;
    }
    if (lane == 63) wsum[wid] = v;
    __syncthreads();
    int wexcl = 0;
#pragma unroll
    for (int i = 0; i < 4; ++i) if (i < wid) wexcl += wsum[i];
    const int total = wsum[0] + wsum[1] + wsum[2] + wsum[3];
    const int gexcl = wexcl + v - s3;            // exclusive prefix of this 4-group
    cumsh[4 * tid + 0] = gexcl + s0;
    cumsh[4 * tid + 1] = gexcl + s1;
    cumsh[4 * tid + 2] = gexcl + s2;
    cumsh[4 * tid + 3] = gexcl + s3;
    __syncthreads();

    float* ob = out + (size_t)b * max_len * H_DIM;

    // ---- replicate: wave owns 4 consecutive source rows -> contiguous stores
#pragma unroll
    for (int i = 0; i < ROWS_PER_WAVE; ++i) {
        const int s  = r0 + i;
        const int en = cumsh[s];
        const int st = s ? cumsh[s - 1] : 0;
        for (int t = st; t < en; ++t) {
            f4* dst = (f4*)(ob + (size_t)t * H_DIM);
            dst[lane]      = v0[i];
            dst[lane + 64] = v1[i];
        }
    }

    // ---- zero the padded tail, one row per wave, stride = waves/batch ----
    const f4 z = (f4)(0.0f);
    const int wv = (bx << 2) | wid;              // 0..255 within this batch
    for (int t = total + wv; t < max_len; t += 4 * BLK_PER_B) {
        f4* dst = (f4*)(ob + (size_t)t * H_DIM);
        dst[lane]      = z;
        dst[lane + 64] = z;
    }

    // ---- mask, partitioned across the batch's 16384 threads ----
    float* mb = mask + (size_t)b * max_len;
    for (int t = (bx << 8) | tid; t < max_len; t += BLK_PER_B * 256) {
        mb[t] = (t < total) ? 0.0f : 1.0f;
    }
}

extern "C" void kernel_launch(void* const* d_in, const int* in_sizes, int n_in,
                              void* d_out, int out_size, void* d_ws, size_t ws_size,
                              hipStream_t stream) {
    const float* x   = (const float*)d_in[0];
    const int*   dur = (const int*)d_in[1];
    float*       out = (float*)d_out;

    const int max_len = out_size / (B_SZ * (H_DIM + 1));
    float* mask = out + (size_t)B_SZ * max_len * H_DIM;

    dim3 grid(BLK_PER_B, B_SZ);
    lr_fused<<<grid, 256, 0, stream>>>(x, dur, out, mask, max_len);
}